// Round 15
// baseline (433.125 us; speedup 1.0000x reference)
//
#include <hip/hip_runtime.h>
#include <hip/hip_bf16.h>
#include <stdint.h>

typedef uint16_t u16;
typedef __attribute__((ext_vector_type(8))) short short8;
typedef __attribute__((ext_vector_type(4))) short short4v;
typedef __attribute__((ext_vector_type(8))) unsigned short ushort8;
typedef __attribute__((ext_vector_type(4))) float f32x4;

#define AS1 __attribute__((address_space(1)))
#define AS3 __attribute__((address_space(3)))

__device__ __forceinline__ float b2f(u16 u){
  union{uint32_t i; float f;} v; v.i=((uint32_t)u)<<16; return v.f;
}
__device__ __forceinline__ u16 f2b(float f){
  union{uint32_t i; float f;} v; v.f=f;
  return (u16)((v.i + 0x7fffu + ((v.i>>16)&1u))>>16);
}
__device__ __forceinline__ u16 f2bf(float f){
  __hip_bfloat16 h = __float2bfloat16(f);
  return *reinterpret_cast<u16*>(&h);
}

// ---------------- fused fp32 -> bf16 conversions (8 segments, 1 launch) -----
struct CvtP { const float* src[8]; u16* dst[8]; long n[8]; };
__global__ void cvt_multi(CvtP p) {
  const int seg = blockIdx.y;
  const long i = ((long)blockIdx.x*256 + threadIdx.x)*8;
  if (i >= p.n[seg]) return;
  const float* in = p.src[seg];
  float4 a = *(const float4*)&in[i];
  float4 b = *(const float4*)&in[i+4];
  ushort8 o;
  o[0]=f2b(a.x); o[1]=f2b(a.y); o[2]=f2b(a.z); o[3]=f2b(a.w);
  o[4]=f2b(b.x); o[5]=f2b(b.y); o[6]=f2b(b.z); o[7]=f2b(b.w);
  *(ushort8*)&p.dst[seg][i] = o;
}

// ---------------------------------------------------------------------------
// NT GEMM, 128x128 tile, BK=32, 8 waves (512 thr).
// Ring of 4 DISTINCT __shared__ buffer pairs + 4x statically-unrolled K-loop,
// 2-deep prefetch with counted s_waitcnt vmcnt(2) (never drained to 0 in
// steady state). Distinct LDS objects defeat the compiler's conservative
// "ds_read may alias in-flight global_load_lds dest" vmcnt(0) insertion that
// serialized the previous dynamic-index double buffer.
// Optional second y-segment (ySplit); optional dual-K (A2); act 2 = gate-comb.
// ---------------------------------------------------------------------------
struct GemmP {
  const u16* A; const u16* B; u16* C; const float* bias;
  const u16* B2; u16* C2; const float* bias2;
  const u16* A2; const u16* lr; const u16* cr;
  long lda, ldb, ldc, ldb2, ldc2;
  int K, Nstore, Nstore2, ySplit, act, outf;   // act: 0 none, 1 sigmoid, 2 gate-comb
  float scale;
};

__global__ __launch_bounds__(512) void gemm_nt(GemmP p) {
  __shared__ __align__(16) u16 lA0[4096]; __shared__ __align__(16) u16 lB0[4096];
  __shared__ __align__(16) u16 lA1[4096]; __shared__ __align__(16) u16 lB1[4096];
  __shared__ __align__(16) u16 lA2[4096]; __shared__ __align__(16) u16 lB2[4096];
  __shared__ __align__(16) u16 lA3[4096]; __shared__ __align__(16) u16 lB3[4096];
  const int t = threadIdx.x;
  const int wave = t >> 6, lane = t & 63;
  int by = blockIdx.y;
  const u16* Bp; u16* Cp; const float* bias; long ldb, ldc; int nst;
  if (by >= p.ySplit) {
    by -= p.ySplit; Bp = p.B2; Cp = p.C2; bias = p.bias2;
    ldb = p.ldb2; ldc = p.ldc2; nst = p.Nstore2;
  } else {
    Bp = p.B; Cp = p.C; bias = p.bias; ldb = p.ldb; ldc = p.ldc; nst = p.Nstore;
  }
  const u16* B = Bp + (long)by * 128 * ldb;
  const int srow = t >> 2, skk = (t & 3) * 8;
  const int wr = wave >> 2, wc = wave & 3;
  const int fr = lane & 15, fk = (lane >> 4) * 8;
  f32x4 acc[4][2] = {};

  const int stepsPerSeg = p.K >> 5;
  const int nseg = p.A2 ? 2 : 1;
  const int total = nseg * stepsPerSeg;           // 32 or 64 -> divisible by 4
  const u16* A0p = p.A + (long)blockIdx.x * 128 * p.lda;
  const u16* A1p = p.A2 ? (p.A2 + (long)blockIdx.x * 128 * p.lda) : A0p;

  auto stage = [&](int s, u16* LA, u16* LB) {
    const int sg = (s >= stepsPerSeg) ? 1 : 0;
    const int k0 = (s - sg*stepsPerSeg) << 5;
    const u16* Ax = sg ? A1p : A0p;
    const u16* Bx = B + (long)sg * p.K;
    __builtin_amdgcn_global_load_lds((const AS1 void*)(Ax + (long)srow*p.lda + k0 + skk),
                                     (AS3 void*)&LA[t*8], 16, 0, 0);
    __builtin_amdgcn_global_load_lds((const AS1 void*)(Bx + (long)srow*ldb + k0 + skk),
                                     (AS3 void*)&LB[t*8], 16, 0, 0);
  };

  auto step = [&](int s, const u16* LA, const u16* LB, u16* SLA, u16* SLB) {
    const bool hs = (s + 2 < total);
    if (hs) stage(s + 2, SLA, SLB);               // 2-deep prefetch in flight
    __builtin_amdgcn_sched_barrier(0);            // pin issue order
    short8 av[4], bv[2];
    #pragma unroll
    for (int mi = 0; mi < 4; ++mi) av[mi] = *(const short8*)&LA[(wr*64 + mi*16 + fr)*32 + fk];
    #pragma unroll
    for (int ni = 0; ni < 2; ++ni) bv[ni] = *(const short8*)&LB[(wc*32 + ni*16 + fr)*32 + fk];
    #pragma unroll
    for (int mi = 0; mi < 4; ++mi)
      #pragma unroll
      for (int ni = 0; ni < 2; ++ni)
        acc[mi][ni] = __builtin_amdgcn_mfma_f32_16x16x32_bf16(av[mi], bv[ni], acc[mi][ni], 0, 0, 0);
    if (hs) asm volatile("s_waitcnt vmcnt(2)" ::: "memory");  // only s+1's loads must land
    else    asm volatile("s_waitcnt vmcnt(0)" ::: "memory");  // tail drain
    __builtin_amdgcn_s_barrier();
    __builtin_amdgcn_sched_barrier(0);
  };

  // prologue: two stages in flight, wait for the first
  stage(0, lA0, lB0);
  stage(1, lA1, lB1);
  asm volatile("s_waitcnt vmcnt(2)" ::: "memory");
  __builtin_amdgcn_s_barrier();
  __builtin_amdgcn_sched_barrier(0);

  for (int s = 0; s < total; s += 4) {
    step(s + 0, lA0, lB0, lA2, lB2);
    step(s + 1, lA1, lB1, lA3, lB3);
    step(s + 2, lA2, lB2, lA0, lB0);
    step(s + 3, lA3, lB3, lA1, lB1);
  }

  const int rbase = blockIdx.x*128 + wr*64;
  const int cbase = by*128 + wc*32;
  const int rsub = (lane >> 4) * 4;
  #pragma unroll
  for (int ni = 0; ni < 2; ++ni) {
    const int col = cbase + ni*16 + fr;
    if (col >= nst) continue;
    const float bs = bias ? bias[col] : 0.f;
    #pragma unroll
    for (int mi = 0; mi < 4; ++mi) {
      #pragma unroll
      for (int j = 0; j < 4; ++j) {
        float v = acc[mi][ni][j] * p.scale + bs;
        const long idx = (long)(rbase + mi*16 + rsub + j) * ldc + col;
        if (p.act == 2) {
          const float gv = 1.f / (1.f + __expf(-v));
          const float cv = b2f(p.cr[idx]);
          const float lv = b2f(p.lr[idx]);
          Cp[idx] = f2b(gv*cv + (1.f - gv)*lv);
        } else {
          if (p.act == 1) v = 1.f / (1.f + __expf(-v));
          if (p.outf) ((float*)Cp)[idx] = v;
          else        Cp[idx] = f2b(v);
        }
      }
    }
  }
}

// ---------------------------------------------------------------------------
// Fused flash attention (unchanged), XCD-aware 1-D grid.
// ---------------------------------------------------------------------------
struct FlashP {
  const u16 *q, *k, *v; u16* o;
  long ldq, ldkv, ldo;
  long qB, kvB, oB;
};

__global__ __launch_bounds__(256) void flash_k(FlashP p) {
  const int t = threadIdx.x, w4 = t >> 6, lane = t & 63;
  const int bid = blockIdx.x;
  const int qt = bid >> 6;
  const int h  = bid & 15;
  const int wz = (bid >> 4) & 3;
  const int fr = lane & 15, g = lane >> 4, fk = g * 8;
  __shared__ __align__(16) u16 kt[64][72];
  __shared__ __align__(16) u16 vt[64][72];
  __shared__ __align__(16) u16 pl[4][32][72];

  const u16* Q = p.q + (long)wz*p.qB + (long)(qt*128 + w4*32)*p.ldq + h*64;
  const u16* K = p.k + (long)wz*p.kvB + h*64;
  const u16* V = p.v + (long)wz*p.kvB + h*64;

  short8 aq[2][2];
  #pragma unroll
  for (int f = 0; f < 2; ++f) {
    aq[f][0] = *(const short8*)&Q[(long)(f*16 + fr)*p.ldq + fk];
    aq[f][1] = *(const short8*)&Q[(long)(f*16 + fr)*p.ldq + 32 + fk];
  }

  f32x4 acc[2][4] = {};
  float ml[2] = {-3e38f, -3e38f}, ll[2] = {0.f, 0.f};
  const float C = 0.125f * 1.44269504f;

  const int krow = t >> 2, kseg = (t & 3) * 16;
  const int vp = t & 31, vc = (t >> 5) * 8;

  short8 kr0, kr1, vr0, vr1;
  kr0 = *(const short8*)&K[(long)krow*p.ldkv + kseg];
  kr1 = *(const short8*)&K[(long)krow*p.ldkv + kseg + 8];
  vr0 = *(const short8*)&V[(long)(2*vp)*p.ldkv + vc];
  vr1 = *(const short8*)&V[(long)(2*vp + 1)*p.ldkv + vc];

  for (int it = 0; it < 16; ++it) {
    *(short8*)&kt[krow][kseg]     = kr0;
    *(short8*)&kt[krow][kseg + 8] = kr1;
    #pragma unroll
    for (int e = 0; e < 8; ++e) {
      const uint32_t pk = (uint32_t)(uint16_t)vr0[e] | ((uint32_t)(uint16_t)vr1[e] << 16);
      *(uint32_t*)&vt[vc + e][2*vp] = pk;
    }
    __syncthreads();

    if (it + 1 < 16) {
      const int kn = (it + 1) * 64;
      kr0 = *(const short8*)&K[(long)(kn + krow)*p.ldkv + kseg];
      kr1 = *(const short8*)&K[(long)(kn + krow)*p.ldkv + kseg + 8];
      vr0 = *(const short8*)&V[(long)(kn + 2*vp)*p.ldkv + vc];
      vr1 = *(const short8*)&V[(long)(kn + 2*vp + 1)*p.ldkv + vc];
    }

    f32x4 s[2][4] = {};
    __builtin_amdgcn_s_setprio(1);
    #pragma unroll
    for (int ni = 0; ni < 4; ++ni) {
      short8 bk0 = *(const short8*)&kt[ni*16 + fr][fk];
      short8 bk1 = *(const short8*)&kt[ni*16 + fr][32 + fk];
      #pragma unroll
      for (int f = 0; f < 2; ++f) {
        s[f][ni] = __builtin_amdgcn_mfma_f32_16x16x32_bf16(bk0, aq[f][0], s[f][ni], 0, 0, 0);
        s[f][ni] = __builtin_amdgcn_mfma_f32_16x16x32_bf16(bk1, aq[f][1], s[f][ni], 0, 0, 0);
      }
    }
    __builtin_amdgcn_s_setprio(0);

    #pragma unroll
    for (int f = 0; f < 2; ++f) {
      float rm = s[f][0][0];
      #pragma unroll
      for (int ni = 0; ni < 4; ++ni)
        #pragma unroll
        for (int j = 0; j < 4; ++j) rm = fmaxf(rm, s[f][ni][j]);
      rm = fmaxf(rm, __shfl_xor(rm, 16, 64));
      rm = fmaxf(rm, __shfl_xor(rm, 32, 64));
      const float rml = rm * C;

      if (__any(rml > ml[f] + 11.5f)) {
        const float mnl = fmaxf(ml[f], rml);
        const float al = exp2f(ml[f] - mnl);
        const float a0 = __shfl(al, g*4 + 0, 64);
        const float a1 = __shfl(al, g*4 + 1, 64);
        const float a2 = __shfl(al, g*4 + 2, 64);
        const float a3 = __shfl(al, g*4 + 3, 64);
        #pragma unroll
        for (int nv = 0; nv < 4; ++nv) {
          acc[f][nv][0] *= a0; acc[f][nv][1] *= a1;
          acc[f][nv][2] *= a2; acc[f][nv][3] *= a3;
        }
        ll[f] *= al;
        ml[f] = mnl;
      }

      float rs = 0.f;
      u16 pb[4][4];
      #pragma unroll
      for (int ni = 0; ni < 4; ++ni)
        #pragma unroll
        for (int j = 0; j < 4; ++j) {
          const float pv = exp2f(s[f][ni][j]*C - ml[f]);
          rs += pv;
          pb[ni][j] = f2bf(pv);
        }
      rs += __shfl_xor(rs, 16, 64);
      rs += __shfl_xor(rs, 32, 64);
      ll[f] += rs;

      #pragma unroll
      for (int ni = 0; ni < 4; ++ni) {
        short4v pk4;
        pk4[0] = (short)pb[ni][0]; pk4[1] = (short)pb[ni][1];
        pk4[2] = (short)pb[ni][2]; pk4[3] = (short)pb[ni][3];
        *(short4v*)&pl[w4][f*16 + fr][ni*16 + g*4] = pk4;
      }
    }

    __builtin_amdgcn_s_setprio(1);
    #pragma unroll
    for (int ks = 0; ks < 2; ++ks) {
      short8 pa0 = *(const short8*)&pl[w4][fr][ks*32 + fk];
      short8 pa1 = *(const short8*)&pl[w4][16 + fr][ks*32 + fk];
      #pragma unroll
      for (int nv = 0; nv < 4; ++nv) {
        short8 bvv = *(const short8*)&vt[nv*16 + fr][ks*32 + fk];
        acc[0][nv] = __builtin_amdgcn_mfma_f32_16x16x32_bf16(pa0, bvv, acc[0][nv], 0, 0, 0);
        acc[1][nv] = __builtin_amdgcn_mfma_f32_16x16x32_bf16(pa1, bvv, acc[1][nv], 0, 0, 0);
      }
    }
    __builtin_amdgcn_s_setprio(0);
    __syncthreads();
  }

  u16* O = p.o + (long)wz*p.oB + (long)(qt*128 + w4*32)*p.ldo + h*64;
  #pragma unroll
  for (int f = 0; f < 2; ++f) {
    const float l0 = __shfl(ll[f], g*4 + 0, 64);
    const float l1 = __shfl(ll[f], g*4 + 1, 64);
    const float l2 = __shfl(ll[f], g*4 + 2, 64);
    const float l3 = __shfl(ll[f], g*4 + 3, 64);
    const float inv[4] = {1.f/l0, 1.f/l1, 1.f/l2, 1.f/l3};
    #pragma unroll
    for (int j = 0; j < 4; ++j)
      #pragma unroll
      for (int nv = 0; nv < 4; ++nv)
        O[(long)(f*16 + g*4 + j)*p.ldo + nv*16 + fr] = f2bf(acc[f][nv][j] * inv[j]);
  }
}

// -------- qs = sum_query @ wq^T + bq --------
__global__ void gemv_qs(const float* sq, const float* w, const float* b, float* out) {
  const int t = threadIdx.x, nl = t & 63, kq = t >> 6;
  const int n = blockIdx.x*64 + nl;
  const float* row = w + (long)n * 1024 + kq*256;
  const float* q = sq + kq*256;
  float s = 0.f;
  for (int k = 0; k < 256; k += 4) {
    float4 ww = *(const float4*)&row[k];
    float4 qq = *(const float4*)&q[k];
    s += qq.x*ww.x + qq.y*ww.y + qq.z*ww.z + qq.w*ww.w;
  }
  __shared__ float ps[4][64];
  ps[kq][nl] = s;
  __syncthreads();
  if (t < 64) out[blockIdx.x*64 + t] = ps[0][t]+ps[1][t]+ps[2][t]+ps[3][t] + b[blockIdx.x*64 + t];
}

// ------- summary attention -------
__global__ void sum_attend(const float* qs, const u16* sumkv, float* content, float* pall) {
  const int h = blockIdx.x, w = blockIdx.y, t = threadIdx.x;
  const int lane = t & 63, wv = t >> 6;
  __shared__ float qsh[64];
  __shared__ float sc[1024];
  __shared__ float rmax[4], rsum[4];
  __shared__ float po[4][64];
  if (t < 64) qsh[t] = qs[h*64 + t];
  __syncthreads();
  const u16* kbase = sumkv + (long)w*2097152 + h*64;
  float e[4];
  float mx = -1e30f;
  #pragma unroll
  for (int j = 0; j < 4; ++j) {
    const int k = j*256 + t;
    const u16* krow = kbase + (long)k * 2048;
    float s = 0.f;
    #pragma unroll
    for (int d = 0; d < 64; d += 8) {
      ushort8 kk = *(const ushort8*)&krow[d];
      #pragma unroll
      for (int q = 0; q < 8; ++q) s += qsh[d+q] * b2f(kk[q]);
    }
    s *= 0.125f;
    e[j] = s;
    mx = fmaxf(mx, s);
  }
  #pragma unroll
  for (int o = 32; o; o >>= 1) mx = fmaxf(mx, __shfl_xor(mx, o, 64));
  if (lane == 0) rmax[wv] = mx;
  __syncthreads();
  mx = fmaxf(fmaxf(rmax[0],rmax[1]), fmaxf(rmax[2],rmax[3]));
  float sum = 0.f;
  #pragma unroll
  for (int j = 0; j < 4; ++j) { e[j] = __expf(e[j]-mx); sum += e[j]; }
  #pragma unroll
  for (int o = 32; o; o >>= 1) sum += __shfl_xor(sum, o, 64);
  if (lane == 0) rsum[wv] = sum;
  __syncthreads();
  const float inv = 1.f / (rsum[0]+rsum[1]+rsum[2]+rsum[3]);
  float* pr = pall + ((long)w*16 + h)*1024;
  #pragma unroll
  for (int j = 0; j < 4; ++j) {
    const int k = j*256 + t;
    const float pn = e[j]*inv;
    sc[k] = pn;
    pr[k] = pn;
  }
  __syncthreads();
  const u16* vbase = sumkv + (long)w*2097152 + 1024 + h*64;
  float o = 0.f;
  const int k0 = wv*256;
  for (int k = k0; k < k0+256; ++k) o += sc[k] * b2f(vbase[(long)k*2048 + lane]);
  po[wv][lane] = o;
  __syncthreads();
  if (t < 64) content[(long)w*1024 + h*64 + t] = po[0][t]+po[1][t]+po[2][t]+po[3][t];
}

__global__ void wavg_k(const float* pall, float* wavg) {
  const int w = blockIdx.y, k = blockIdx.x*256 + threadIdx.x;
  float s = 0.f;
  #pragma unroll
  for (int h = 0; h < 16; ++h) s += pall[((long)w*16 + h)*1024 + k];
  wavg[w*1024 + k] = s * (1.f/16.f);
}

// ------- content projection -------
__global__ void contproj_k(const float* content, const float* w_, const float* b, float* out) {
  const int w = blockIdx.y, t = threadIdx.x;
  const int nl = t & 63, kq = t >> 6;
  const int n = blockIdx.x*64 + nl;
  const float* c = content + w*1024 + kq*256;
  const float* row = w_ + (long)n * 1024 + kq*256;
  float s = 0.f;
  for (int k = 0; k < 256; k += 4) {
    float4 ww = *(const float4*)&row[k];
    s += c[k]*ww.x + c[k+1]*ww.y + c[k+2]*ww.z + c[k+3]*ww.w;
  }
  __shared__ float ps[4][64];
  ps[kq][nl] = s;
  __syncthreads();
  if (t < 64) out[w*1024 + blockIdx.x*64 + t] = ps[0][t]+ps[1][t]+ps[2][t]+ps[3][t] + b[blockIdx.x*64 + t];
}

// ------- attn_stats phase A -------
__global__ void stats1_k(const float* wavg, float* part) {
  const int c = blockIdx.x, w = blockIdx.y, t = threadIdx.x;
  __shared__ float a[1024];
  for (int i = t; i < 1024; i += 256) a[i] = wavg[w*1024 + i];
  __syncthreads();
  const int jl = t & 63, iq = t >> 6;
  const int j = c*64 + jl;
  const float aj = a[j];
  int pr = 0;
  const int i0 = iq*256;
  #pragma unroll 8
  for (int i = i0; i < i0+256; ++i) {
    const float ai = a[i];
    pr += (ai < aj) || (ai == aj && i < j);
  }
  __shared__ int prs[4][64];
  prs[iq][jl] = pr;
  __syncthreads();
  if (t < 64) {
    const int rank = 1 + prs[0][jl] + prs[1][jl] + prs[2][jl] + prs[3][jl];
    float ent = -aj * logf(aj + 1e-8f);
    float gnum = (float)rank * aj;
    float ssum = aj;
    float mx = aj;
    float top5 = (rank >= 1020) ? aj : 0.f;
    #pragma unroll
    for (int o = 32; o; o >>= 1) {
      ent += __shfl_xor(ent, o, 64);
      gnum += __shfl_xor(gnum, o, 64);
      ssum += __shfl_xor(ssum, o, 64);
      mx = fmaxf(mx, __shfl_xor(mx, o, 64));
      top5 += __shfl_xor(top5, o, 64);
    }
    if (t == 0) {
      float* pp = part + ((w*16 + c) * 5);
      pp[0]=ent; pp[1]=gnum; pp[2]=ssum; pp[3]=mx; pp[4]=top5;
    }
  }
}

// ------- attn_stats phase B -------
__global__ void stats2_k(const float* part, float* stats) {
  const int w = blockIdx.x, t = threadIdx.x;
  const int c = t & 15, stat = t >> 4;
  float v = 0.f;
  const bool active = stat < 5;
  if (active) v = part[(w*16 + c)*5 + stat];
  #pragma unroll
  for (int o = 8; o; o >>= 1) {
    const float ov = __shfl_xor(v, o, 64);
    v = (stat == 3) ? fmaxf(v, ov) : (v + ov);
  }
  __shared__ float r5[5];
  if (active && c == 0) r5[stat] = v;
  __syncthreads();
  if (t == 0) {
    stats[w*4+0] = r5[0];
    stats[w*4+1] = 2.f*r5[1]/(1024.f*r5[2] + 1e-8f) - 1025.f/1024.f;
    stats[w*4+2] = r5[3];
    stats[w*4+3] = r5[4];
  }
}

// ------- pat MLP + summary combine -------
__global__ void patsum_k(const float* stats, const float* contprj,
                         const float* pw1, const float* pb1, const float* pw2, const float* pb2,
                         const float* combw, const float* combb, float* summ) {
  const int w = blockIdx.x, t = threadIdx.x;
  const int nl = t & 63, kq = t >> 6;
  __shared__ float p1[64], pat[64];
  __shared__ float ps[4][64];
  __shared__ float ps2[4][64];
  if (t < 64) {
    float s = 0.f;
    #pragma unroll
    for (int k = 0; k < 4; ++k) s += stats[w*4+k] * pw1[t*4+k];
    p1[t] = fmaxf(s + pb1[t], 0.f);
  }
  __syncthreads();
  {
    float s = 0.f;
    const float* rw = pw2 + (long)nl*64 + kq*16;
    const float* pp = p1 + kq*16;
    #pragma unroll
    for (int k = 0; k < 16; ++k) s += pp[k] * rw[k];
    ps[kq][nl] = s;
  }
  __syncthreads();
  if (t < 64) pat[t] = ps[0][t]+ps[1][t]+ps[2][t]+ps[3][t] + pb2[t];
  __syncthreads();
  const float* c = contprj + w*1024;
  const float* row = combw + (long)nl * 1088;
  float s = 0.f;
  const int k0 = kq*272;
  for (int k = k0; k < k0+272; ++k) {
    const float rv = row[k];
    const float cv = (k < 1024) ? c[k] : pat[k-1024];
    s += cv * rv;
  }
  ps2[kq][nl] = s;
  __syncthreads();
  if (t < 64) summ[w*64 + t] = ps2[0][t]+ps2[1][t]+ps2[2][t]+ps2[3][t] + combb[t];
}

// ---------------- meta attention + routing ----------------
__global__ void meta_k(const float* summ, const float* miw, const float* mib,
                       const float* mow, const float* mob, const float* rw1, const float* rb1,
                       const float* rw2, const float* rb2, float* routing) {
  const int t = threadIdx.x;
  __shared__ float qkv[4][192];
  __shared__ float sc[64];
  __shared__ float o[4][64];
  __shared__ float rf[4][64];
  __shared__ float t1[4][64];
  __shared__ float lg[4];
  for (int idx = t; idx < 768; idx += 64) {
    const int w = idx / 192, rrow = idx % 192;
    const float* rw = miw + (long)rrow * 64;
    float s = 0.f;
    for (int k = 0; k < 64; ++k) s += summ[w*64+k] * rw[k];
    qkv[w][rrow] = s + mib[rrow];
  }
  __syncthreads();
  {
    const int h = t >> 4, i = (t >> 2) & 3, j = t & 3;
    float s = 0.f;
    #pragma unroll
    for (int d = 0; d < 16; ++d) s += qkv[i][h*16+d] * qkv[j][64 + h*16+d];
    sc[t] = s * 0.25f;
  }
  __syncthreads();
  if (t < 16) {
    const float a0=sc[t*4], a1=sc[t*4+1], a2=sc[t*4+2], a3=sc[t*4+3];
    const float m = fmaxf(fmaxf(a0,a1), fmaxf(a2,a3));
    const float e0=__expf(a0-m), e1=__expf(a1-m), e2=__expf(a2-m), e3=__expf(a3-m);
    const float s = e0+e1+e2+e3;
    sc[t*4]=e0/s; sc[t*4+1]=e1/s; sc[t*4+2]=e2/s; sc[t*4+3]=e3/s;
  }
  __syncthreads();
  for (int idx = t; idx < 256; idx += 64) {
    const int i = idx >> 6, c = idx & 63, h = c >> 4;
    float s = 0.f;
    #pragma unroll
    for (int j = 0; j < 4; ++j) s += sc[(h*4+i)*4+j] * qkv[j][128 + c];
    o[i][c] = s;
  }
  __syncthreads();
  for (int idx = t; idx < 256; idx += 64) {
    const int i = idx >> 6, n = idx & 63;
    const float* rw = mow + (long)n * 64;
    float s = 0.f;
    for (int k = 0; k < 64; ++k) s += o[i][k] * rw[k];
    rf[i][n] = s + mob[n];
  }
  __syncthreads();
  for (int idx = t; idx < 256; idx += 64) {
    const int i = idx >> 6, n = idx & 63;
    const float* rw = rw1 + (long)n * 64;
    float s = 0.f;
    for (int k = 0; k < 64; ++k) s += rf[i][k] * rw[k];
    t1[i][n] = fmaxf(s + rb1[n], 0.f);
  }
  __syncthreads();
  if (t < 4) {
    float s = 0.f;
    for (int k = 0; k < 64; ++k) s += t1[t][k] * rw2[k];
    lg[t] = s + rb2[0];
  }
  __syncthreads();
  if (t == 0) {
    const float m = fmaxf(fmaxf(lg[0],lg[1]), fmaxf(lg[2],lg[3]));
    float e[4], s = 0.f;
    #pragma unroll
    for (int i = 0; i < 4; ++i) { e[i] = __expf(lg[i]-m); s += e[i]; }
    #pragma unroll
    for (int i = 0; i < 4; ++i) routing[i] = e[i]/s;
  }
}

// ---------------- routing-weighted kv mix ----------------
__global__ void kvr_k(const u16* local, const float* routing, u16* kvr) {
  const int r = blockIdx.y;
  const long e = ((long)blockIdx.x*256 + threadIdx.x) * 8;
  float rm[4]; float s = 0.f;
  #pragma unroll
  for (int w = 0; w < 4; ++w) { rm[w] = (w == r) ? 0.f : routing[w]; s += rm[w]; }
  const float inv = 1.f / (s + 1e-8f);
  ushort8 a0 = *(const ushort8*)&local[e];
  ushort8 a1 = *(const ushort8*)&local[1048576 + e];
  ushort8 a2 = *(const ushort8*)&local[2097152 + e];
  ushort8 a3 = *(const ushort8*)&local[3145728 + e];
  ushort8 out;
  #pragma unroll
  for (int j = 0; j < 8; ++j)
    out[j] = f2b((rm[0]*b2f(a0[j]) + rm[1]*b2f(a1[j]) + rm[2]*b2f(a2[j]) + rm[3]*b2f(a3[j])) * inv);
  *(ushort8*)&kvr[(long)r*1048576 + e] = out;
}

// ---------------------------------------------------------------------------
static void gemm1(hipStream_t st, dim3 grid,
                  const u16* A, long lda, const u16* B, long ldb,
                  u16* C, long ldc, const float* bias,
                  int K, int N, float scale, int act, int outf) {
  GemmP p = {};
  p.A=A; p.B=B; p.C=C; p.bias=bias;
  p.lda=lda; p.ldb=ldb; p.ldc=ldc;
  p.K=K; p.Nstore=N; p.ySplit=1<<30; p.act=act; p.outf=outf; p.scale=scale;
  gemm_nt<<<grid, dim3(512), 0, st>>>(p);
}

extern "C" void kernel_launch(void* const* d_in, const int* in_sizes, int n_in,
                              void* d_out, int out_size, void* d_ws, size_t ws_size,
                              hipStream_t stream) {
  (void)in_sizes; (void)n_in; (void)out_size; (void)ws_size;
  const float* x   = (const float*)d_in[0];
  const float* liw = (const float*)d_in[1];
  const float* lib = (const float*)d_in[2];
  const float* low = (const float*)d_in[3];
  const float* lob = (const float*)d_in[4];
  const float* sq  = (const float*)d_in[5];
  const float* siw = (const float*)d_in[6];
  const float* sib = (const float*)d_in[7];
  const float* sow = (const float*)d_in[8];
  const float* sob = (const float*)d_in[9];
  const float* pw1 = (const float*)d_in[10];
  const float* pb1 = (const float*)d_in[11];
  const float* pw2 = (const float*)d_in[12];
  const float* pb2 = (const float*)d_in[13];
  const float* cbw = (const float*)d_in[14];
  const float* cbb = (const float*)d_in[15];
  const float* miw = (const float*)d_in[16];
  const float* mib = (const float*)d_in[17];
  const float* mow = (const float*)d_in[18];
  const float* mob = (const float*)d_in[19];
  const float* rw1 = (const float*)d_in[20];
  const float* rb1 = (const float*)d_in[21];
  const float* rw2 = (const float*)d_in[22];
  const float* rb2 = (const float*)d_in[23];
  const float* ciw = (const float*)d_in[24];
  const float* cib = (const float*)d_in[25];
  const float* cow = (const float*)d_in[26];
  const float* cob = (const float*)d_in[27];
  const float* gw  = (const float*)d_in[28];
  const float* gb  = (const float*)d_in[29];
  const float* pw  = (const float*)d_in[30];
  const float* pb  = (const float*)d_in[31];

  char* ws = (char*)d_ws;
  u16* qkv    = (u16*)(ws + 0);
  u16* aout   = (u16*)(ws + 25165824);
  u16* local  = (u16*)(ws + 33554432);
  u16* scratch= (u16*)(ws + 41943040);
  u16* s2048  = (u16*)(ws + 79691776);
  u16* cq     = (u16*)(ws + 96468992);
  u16* kvr    = (u16*)(ws + 104857600);
  u16* crossb = (u16*)(ws + 113246208);
  char* sf = ws + 121634816;
  float* qs      = (float*)(sf + 0);
  float* pall    = (float*)(sf + 4096);
  float* wavg    = (float*)(sf + 266240);
  float* content = (float*)(sf + 282624);
  float* contprj = (float*)(sf + 299008);
  float* stats   = (float*)(sf + 315392);
  float* summ    = (float*)(sf + 315456);
  float* routing = (float*)(sf + 316480);
  float* part    = (float*)(sf + 316544);
  u16* siwkvb = (u16*)(ws + 122028032);
  u16* lowb   = (u16*)(ws + 126222336);
  u16* ciwb   = (u16*)(ws + 128319488);
  u16* cowb   = (u16*)(ws + 134610944);
  u16* gwb    = (u16*)(ws + 136708096);
  u16* pwb    = (u16*)(ws + 140902400);
  u16* xb   = crossb;
  u16* liwb = scratch;

  // 0. fp32 -> bf16 conversions
  CvtP cp;
  cp.src[0]=x;   cp.dst[0]=xb;     cp.n[0]=4194304;
  cp.src[1]=liw; cp.dst[1]=liwb;   cp.n[1]=3145728;
  cp.src[2]=low; cp.dst[2]=lowb;   cp.n[2]=1048576;
  cp.src[3]=siw+1048576; cp.dst[3]=siwkvb; cp.n[3]=2097152;
  cp.src[4]=ciw; cp.dst[4]=ciwb;   cp.n[4]=3145728;
  cp.src[5]=cow; cp.dst[5]=cowb;   cp.n[5]=1048576;
  cp.src[6]=gw;  cp.dst[6]=gwb;    cp.n[6]=2097152;
  cp.src[7]=pw;  cp.dst[7]=pwb;    cp.n[7]=1048576;
  cvt_multi<<<dim3(2048, 8), dim3(256), 0, stream>>>(cp);

  // 1. local QKV projection
  gemm1(stream, dim3(32,24), xb,1024, liwb,1024, qkv,3072, lib, 1024, 3072, 1.f, 0, 0);

  // 2. fused local self-attention (XCD-swizzled 1-D grid)
  {
    FlashP fp;
    fp.q = qkv; fp.k = qkv + 1024; fp.v = qkv + 2048; fp.o = aout;
    fp.ldq = 3072; fp.ldkv = 3072; fp.ldo = 1024;
    fp.qB = 3145728; fp.kvB = 3145728; fp.oB = 1048576;
    flash_k<<<dim3(512), dim3(256), 0, stream>>>(fp);
  }

  // 3. local out-projection
  gemm1(stream, dim3(32,8), aout,1024, lowb,1024, local,1024, lob, 1024, 1024, 1.f, 0, 0);

  // 4. combined crossQ (y<8) + summary K/V (y>=8) projections
  {
    GemmP p = {};
    p.A = local; p.lda = 1024; p.K = 1024; p.scale = 1.f;
    p.B = ciwb;   p.C = cq;    p.bias = cib;      p.ldb = 1024; p.ldc = 1024; p.Nstore = 1024;
    p.B2 = siwkvb; p.C2 = s2048; p.bias2 = sib+1024; p.ldb2 = 1024; p.ldc2 = 2048; p.Nstore2 = 2048;
    p.ySplit = 8;
    gemm_nt<<<dim3(32,24), dim3(512), 0, stream>>>(p);
  }

  // 5. summaries
  gemv_qs<<<dim3(16), dim3(256), 0, stream>>>(sq, siw, sib, qs);
  sum_attend<<<dim3(16,4), dim3(256), 0, stream>>>(qs, s2048, content, pall);
  wavg_k<<<dim3(4,4), dim3(256), 0, stream>>>(pall, wavg);
  contproj_k<<<dim3(16,4), dim3(256), 0, stream>>>(content, sow, sob, contprj);
  stats1_k<<<dim3(16,4), dim3(256), 0, stream>>>(wavg, part);
  stats2_k<<<dim3(4), dim3(128), 0, stream>>>(part, stats);
  patsum_k<<<dim3(4), dim3(256), 0, stream>>>(stats, contprj, pw1, pb1, pw2, pb2, cbw, cbb, summ);

  // 6. meta attention + routing
  meta_k<<<dim3(1), dim3(64), 0, stream>>>(summ, miw, mib, mow, mob, rw1, rb1, rw2, rb2, routing);

  // 7. per-rank mixed kv
  kvr_k<<<dim3(512,4), dim3(256), 0, stream>>>(local, routing, kvr);

  // 8. cross K/V projection
  gemm1(stream, dim3(32,16), kvr,1024, ciwb+1048576,1024, s2048,2048, cib+1024, 1024, 2048, 1.f, 0, 0);

  // 9. fused cross attention (XCD-swizzled 1-D grid)
  {
    FlashP fp;
    fp.q = cq; fp.k = s2048; fp.v = s2048 + 1024; fp.o = aout;
    fp.ldq = 1024; fp.ldkv = 2048; fp.ldo = 1024;
    fp.qB = 1048576; fp.kvB = 2097152; fp.oB = 1048576;
    flash_k<<<dim3(512), dim3(256), 0, stream>>>(fp);
  }

  // 10. cross out-projection
  gemm1(stream, dim3(32,8), aout,1024, cowb,1024, crossb,1024, cob, 1024, 1024, 1.f, 0, 0);

  // 11. gate GEMM (dual-K: local@gw_l + cross@gw_c) with fused sigmoid+comb
  {
    GemmP p = {};
    p.A = local; p.A2 = crossb; p.lr = local; p.cr = crossb;
    p.B = gwb; p.C = kvr; p.bias = gb;
    p.lda = 1024; p.ldb = 2048; p.ldc = 1024;
    p.K = 1024; p.Nstore = 1024; p.ySplit = 1<<30; p.act = 2; p.outf = 0; p.scale = 1.f;
    gemm_nt<<<dim3(32,8), dim3(512), 0, stream>>>(p);
  }

  // 12. final projection -> d_out (fp32)
  gemm1(stream, dim3(32,8), kvr,1024, pwb,1024, (u16*)d_out,1024, pb, 1024, 1024, 1.f, 0, 1);
}

// Round 16
// 424.284 us; speedup vs baseline: 1.0208x; 1.0208x over previous
//
#include <hip/hip_runtime.h>
#include <hip/hip_bf16.h>
#include <stdint.h>

typedef uint16_t u16;
typedef __attribute__((ext_vector_type(8))) short short8;
typedef __attribute__((ext_vector_type(4))) short short4v;
typedef __attribute__((ext_vector_type(8))) unsigned short ushort8;
typedef __attribute__((ext_vector_type(4))) float f32x4;

#define AS1 __attribute__((address_space(1)))
#define AS3 __attribute__((address_space(3)))

__device__ __forceinline__ float b2f(u16 u){
  union{uint32_t i; float f;} v; v.i=((uint32_t)u)<<16; return v.f;
}
__device__ __forceinline__ u16 f2b(float f){
  union{uint32_t i; float f;} v; v.f=f;
  return (u16)((v.i + 0x7fffu + ((v.i>>16)&1u))>>16);
}
__device__ __forceinline__ u16 f2bf(float f){
  __hip_bfloat16 h = __float2bfloat16(f);
  return *reinterpret_cast<u16*>(&h);
}

// ---------------- fused fp32 -> bf16 conversions (8 segments, 1 launch) -----
struct CvtP { const float* src[8]; u16* dst[8]; long n[8]; };
__global__ void cvt_multi(CvtP p) {
  const int seg = blockIdx.y;
  const long i = ((long)blockIdx.x*256 + threadIdx.x)*8;
  if (i >= p.n[seg]) return;
  const float* in = p.src[seg];
  float4 a = *(const float4*)&in[i];
  float4 b = *(const float4*)&in[i+4];
  ushort8 o;
  o[0]=f2b(a.x); o[1]=f2b(a.y); o[2]=f2b(a.z); o[3]=f2b(a.w);
  o[4]=f2b(b.x); o[5]=f2b(b.y); o[6]=f2b(b.z); o[7]=f2b(b.w);
  *(ushort8*)&p.dst[seg][i] = o;
}

// ---------------------------------------------------------------------------
// NT GEMM, BMx128 tile (BM=128 or 64), BK=32, 8 waves (512 thr), dbuf LDS.
// BM=64 doubles the grid for N=1024 GEMMs (512 blocks = 2/CU) so independent
// blocks overlap each other's barrier drains (the QKV dispatch at 3/CU runs
// 2.6x better per column than 1/CU N=1024 dispatches). BN stays 128 so
// A-refetch is unchanged and extra B-refetch is absorbed by per-XCD L2.
// Optional second y-segment (ySplit); optional dual-K (A2); act 2 = gate-comb.
// ---------------------------------------------------------------------------
struct GemmP {
  const u16* A; const u16* B; u16* C; const float* bias;
  const u16* B2; u16* C2; const float* bias2;
  const u16* A2; const u16* lr; const u16* cr;
  long lda, ldb, ldc, ldb2, ldc2;
  int K, Nstore, Nstore2, ySplit, act, outf;   // act: 0 none, 1 sigmoid, 2 gate-comb
  float scale;
};

template<int BM>
__global__ __launch_bounds__(512) void gemm_nt(GemmP p) {
  constexpr int MI = BM / 32;            // MFMA row-frags per wave (4 or 2)
  __shared__ __align__(16) u16 lA[2][BM*32];
  __shared__ __align__(16) u16 lB[2][4096];
  const int t = threadIdx.x;
  const int wave = t >> 6, lane = t & 63;
  int by = blockIdx.y;
  const u16* Bp; u16* Cp; const float* bias; long ldb, ldc; int nst;
  if (by >= p.ySplit) {
    by -= p.ySplit; Bp = p.B2; Cp = p.C2; bias = p.bias2;
    ldb = p.ldb2; ldc = p.ldc2; nst = p.Nstore2;
  } else {
    Bp = p.B; Cp = p.C; bias = p.bias; ldb = p.ldb; ldc = p.ldc; nst = p.Nstore;
  }
  const u16* B = Bp + (long)by * 128 * ldb;
  const int srow = t >> 2, skk = (t & 3) * 8;
  const int wr = wave >> 2, wc = wave & 3;   // 2 row-waves x 4 col-waves
  const int fr = lane & 15, fk = (lane >> 4) * 8;
  f32x4 acc[MI][2] = {};

  const int stepsPerSeg = p.K >> 5;
  const int nseg = p.A2 ? 2 : 1;
  const int total = nseg * stepsPerSeg;
  const u16* A0p = p.A + (long)blockIdx.x * BM * p.lda;
  const u16* A1p = p.A2 ? (p.A2 + (long)blockIdx.x * BM * p.lda) : A0p;

  auto stage = [&](int s, int b) {
    const int sg = (s >= stepsPerSeg) ? 1 : 0;
    const int k0 = (s - sg*stepsPerSeg) << 5;
    const u16* Ax = sg ? A1p : A0p;
    const u16* Bx = B + (long)sg * p.K;
    if (t < BM*4)
      __builtin_amdgcn_global_load_lds((const AS1 void*)(Ax + (long)srow*p.lda + k0 + skk),
                                       (AS3 void*)&lA[b][t*8], 16, 0, 0);
    __builtin_amdgcn_global_load_lds((const AS1 void*)(Bx + (long)srow*ldb + k0 + skk),
                                     (AS3 void*)&lB[b][t*8], 16, 0, 0);
  };

  stage(0, 0);
  __syncthreads();
  int cur = 0;
  for (int s = 0; s < total; ++s) {
    if (s + 1 < total) stage(s + 1, cur ^ 1);
    short8 av[MI], bv[2];
    #pragma unroll
    for (int mi = 0; mi < MI; ++mi) av[mi] = *(const short8*)&lA[cur][(wr*(BM/2) + mi*16 + fr)*32 + fk];
    #pragma unroll
    for (int ni = 0; ni < 2; ++ni) bv[ni] = *(const short8*)&lB[cur][(wc*32 + ni*16 + fr)*32 + fk];
    #pragma unroll
    for (int mi = 0; mi < MI; ++mi)
      #pragma unroll
      for (int ni = 0; ni < 2; ++ni)
        acc[mi][ni] = __builtin_amdgcn_mfma_f32_16x16x32_bf16(av[mi], bv[ni], acc[mi][ni], 0, 0, 0);
    __syncthreads();
    cur ^= 1;
  }

  const int rbase = blockIdx.x*BM + wr*(BM/2);
  const int cbase = by*128 + wc*32;
  const int rsub = (lane >> 4) * 4;
  #pragma unroll
  for (int ni = 0; ni < 2; ++ni) {
    const int col = cbase + ni*16 + fr;
    if (col >= nst) continue;
    const float bs = bias ? bias[col] : 0.f;
    #pragma unroll
    for (int mi = 0; mi < MI; ++mi) {
      #pragma unroll
      for (int j = 0; j < 4; ++j) {
        float v = acc[mi][ni][j] * p.scale + bs;
        const long idx = (long)(rbase + mi*16 + rsub + j) * ldc + col;
        if (p.act == 2) {
          const float gv = 1.f / (1.f + __expf(-v));
          const float cv = b2f(p.cr[idx]);
          const float lv = b2f(p.lr[idx]);
          Cp[idx] = f2b(gv*cv + (1.f - gv)*lv);
        } else {
          if (p.act == 1) v = 1.f / (1.f + __expf(-v));
          if (p.outf) ((float*)Cp)[idx] = v;
          else        Cp[idx] = f2b(v);
        }
      }
    }
  }
}

// ---------------------------------------------------------------------------
// Fused flash attention (unchanged from Round 10), XCD-aware 1-D grid.
// ---------------------------------------------------------------------------
struct FlashP {
  const u16 *q, *k, *v; u16* o;
  long ldq, ldkv, ldo;
  long qB, kvB, oB;
};

__global__ __launch_bounds__(256) void flash_k(FlashP p) {
  const int t = threadIdx.x, w4 = t >> 6, lane = t & 63;
  const int bid = blockIdx.x;
  const int qt = bid >> 6;
  const int h  = bid & 15;
  const int wz = (bid >> 4) & 3;
  const int fr = lane & 15, g = lane >> 4, fk = g * 8;
  __shared__ __align__(16) u16 kt[64][72];
  __shared__ __align__(16) u16 vt[64][72];
  __shared__ __align__(16) u16 pl[4][32][72];

  const u16* Q = p.q + (long)wz*p.qB + (long)(qt*128 + w4*32)*p.ldq + h*64;
  const u16* K = p.k + (long)wz*p.kvB + h*64;
  const u16* V = p.v + (long)wz*p.kvB + h*64;

  short8 aq[2][2];
  #pragma unroll
  for (int f = 0; f < 2; ++f) {
    aq[f][0] = *(const short8*)&Q[(long)(f*16 + fr)*p.ldq + fk];
    aq[f][1] = *(const short8*)&Q[(long)(f*16 + fr)*p.ldq + 32 + fk];
  }

  f32x4 acc[2][4] = {};
  float ml[2] = {-3e38f, -3e38f}, ll[2] = {0.f, 0.f};
  const float C = 0.125f * 1.44269504f;

  const int krow = t >> 2, kseg = (t & 3) * 16;
  const int vp = t & 31, vc = (t >> 5) * 8;

  short8 kr0, kr1, vr0, vr1;
  kr0 = *(const short8*)&K[(long)krow*p.ldkv + kseg];
  kr1 = *(const short8*)&K[(long)krow*p.ldkv + kseg + 8];
  vr0 = *(const short8*)&V[(long)(2*vp)*p.ldkv + vc];
  vr1 = *(const short8*)&V[(long)(2*vp + 1)*p.ldkv + vc];

  for (int it = 0; it < 16; ++it) {
    *(short8*)&kt[krow][kseg]     = kr0;
    *(short8*)&kt[krow][kseg + 8] = kr1;
    #pragma unroll
    for (int e = 0; e < 8; ++e) {
      const uint32_t pk = (uint32_t)(uint16_t)vr0[e] | ((uint32_t)(uint16_t)vr1[e] << 16);
      *(uint32_t*)&vt[vc + e][2*vp] = pk;
    }
    __syncthreads();

    if (it + 1 < 16) {
      const int kn = (it + 1) * 64;
      kr0 = *(const short8*)&K[(long)(kn + krow)*p.ldkv + kseg];
      kr1 = *(const short8*)&K[(long)(kn + krow)*p.ldkv + kseg + 8];
      vr0 = *(const short8*)&V[(long)(kn + 2*vp)*p.ldkv + vc];
      vr1 = *(const short8*)&V[(long)(kn + 2*vp + 1)*p.ldkv + vc];
    }

    f32x4 s[2][4] = {};
    __builtin_amdgcn_s_setprio(1);
    #pragma unroll
    for (int ni = 0; ni < 4; ++ni) {
      short8 bk0 = *(const short8*)&kt[ni*16 + fr][fk];
      short8 bk1 = *(const short8*)&kt[ni*16 + fr][32 + fk];
      #pragma unroll
      for (int f = 0; f < 2; ++f) {
        s[f][ni] = __builtin_amdgcn_mfma_f32_16x16x32_bf16(bk0, aq[f][0], s[f][ni], 0, 0, 0);
        s[f][ni] = __builtin_amdgcn_mfma_f32_16x16x32_bf16(bk1, aq[f][1], s[f][ni], 0, 0, 0);
      }
    }
    __builtin_amdgcn_s_setprio(0);

    #pragma unroll
    for (int f = 0; f < 2; ++f) {
      float rm = s[f][0][0];
      #pragma unroll
      for (int ni = 0; ni < 4; ++ni)
        #pragma unroll
        for (int j = 0; j < 4; ++j) rm = fmaxf(rm, s[f][ni][j]);
      rm = fmaxf(rm, __shfl_xor(rm, 16, 64));
      rm = fmaxf(rm, __shfl_xor(rm, 32, 64));
      const float rml = rm * C;

      if (__any(rml > ml[f] + 11.5f)) {
        const float mnl = fmaxf(ml[f], rml);
        const float al = exp2f(ml[f] - mnl);
        const float a0 = __shfl(al, g*4 + 0, 64);
        const float a1 = __shfl(al, g*4 + 1, 64);
        const float a2 = __shfl(al, g*4 + 2, 64);
        const float a3 = __shfl(al, g*4 + 3, 64);
        #pragma unroll
        for (int nv = 0; nv < 4; ++nv) {
          acc[f][nv][0] *= a0; acc[f][nv][1] *= a1;
          acc[f][nv][2] *= a2; acc[f][nv][3] *= a3;
        }
        ll[f] *= al;
        ml[f] = mnl;
      }

      float rs = 0.f;
      u16 pb[4][4];
      #pragma unroll
      for (int ni = 0; ni < 4; ++ni)
        #pragma unroll
        for (int j = 0; j < 4; ++j) {
          const float pv = exp2f(s[f][ni][j]*C - ml[f]);
          rs += pv;
          pb[ni][j] = f2bf(pv);
        }
      rs += __shfl_xor(rs, 16, 64);
      rs += __shfl_xor(rs, 32, 64);
      ll[f] += rs;

      #pragma unroll
      for (int ni = 0; ni < 4; ++ni) {
        short4v pk4;
        pk4[0] = (short)pb[ni][0]; pk4[1] = (short)pb[ni][1];
        pk4[2] = (short)pb[ni][2]; pk4[3] = (short)pb[ni][3];
        *(short4v*)&pl[w4][f*16 + fr][ni*16 + g*4] = pk4;
      }
    }

    __builtin_amdgcn_s_setprio(1);
    #pragma unroll
    for (int ks = 0; ks < 2; ++ks) {
      short8 pa0 = *(const short8*)&pl[w4][fr][ks*32 + fk];
      short8 pa1 = *(const short8*)&pl[w4][16 + fr][ks*32 + fk];
      #pragma unroll
      for (int nv = 0; nv < 4; ++nv) {
        short8 bvv = *(const short8*)&vt[nv*16 + fr][ks*32 + fk];
        acc[0][nv] = __builtin_amdgcn_mfma_f32_16x16x32_bf16(pa0, bvv, acc[0][nv], 0, 0, 0);
        acc[1][nv] = __builtin_amdgcn_mfma_f32_16x16x32_bf16(pa1, bvv, acc[1][nv], 0, 0, 0);
      }
    }
    __builtin_amdgcn_s_setprio(0);
    __syncthreads();
  }

  u16* O = p.o + (long)wz*p.oB + (long)(qt*128 + w4*32)*p.ldo + h*64;
  #pragma unroll
  for (int f = 0; f < 2; ++f) {
    const float l0 = __shfl(ll[f], g*4 + 0, 64);
    const float l1 = __shfl(ll[f], g*4 + 1, 64);
    const float l2 = __shfl(ll[f], g*4 + 2, 64);
    const float l3 = __shfl(ll[f], g*4 + 3, 64);
    const float inv[4] = {1.f/l0, 1.f/l1, 1.f/l2, 1.f/l3};
    #pragma unroll
    for (int j = 0; j < 4; ++j)
      #pragma unroll
      for (int nv = 0; nv < 4; ++nv)
        O[(long)(f*16 + g*4 + j)*p.ldo + nv*16 + fr] = f2bf(acc[f][nv][j] * inv[j]);
  }
}

// -------- qs = sum_query @ wq^T + bq --------
__global__ void gemv_qs(const float* sq, const float* w, const float* b, float* out) {
  const int t = threadIdx.x, nl = t & 63, kq = t >> 6;
  const int n = blockIdx.x*64 + nl;
  const float* row = w + (long)n * 1024 + kq*256;
  const float* q = sq + kq*256;
  float s = 0.f;
  for (int k = 0; k < 256; k += 4) {
    float4 ww = *(const float4*)&row[k];
    float4 qq = *(const float4*)&q[k];
    s += qq.x*ww.x + qq.y*ww.y + qq.z*ww.z + qq.w*ww.w;
  }
  __shared__ float ps[4][64];
  ps[kq][nl] = s;
  __syncthreads();
  if (t < 64) out[blockIdx.x*64 + t] = ps[0][t]+ps[1][t]+ps[2][t]+ps[3][t] + b[blockIdx.x*64 + t];
}

// ------- summary attention -------
__global__ void sum_attend(const float* qs, const u16* sumkv, float* content, float* pall) {
  const int h = blockIdx.x, w = blockIdx.y, t = threadIdx.x;
  const int lane = t & 63, wv = t >> 6;
  __shared__ float qsh[64];
  __shared__ float sc[1024];
  __shared__ float rmax[4], rsum[4];
  __shared__ float po[4][64];
  if (t < 64) qsh[t] = qs[h*64 + t];
  __syncthreads();
  const u16* kbase = sumkv + (long)w*2097152 + h*64;
  float e[4];
  float mx = -1e30f;
  #pragma unroll
  for (int j = 0; j < 4; ++j) {
    const int k = j*256 + t;
    const u16* krow = kbase + (long)k * 2048;
    float s = 0.f;
    #pragma unroll
    for (int d = 0; d < 64; d += 8) {
      ushort8 kk = *(const ushort8*)&krow[d];
      #pragma unroll
      for (int q = 0; q < 8; ++q) s += qsh[d+q] * b2f(kk[q]);
    }
    s *= 0.125f;
    e[j] = s;
    mx = fmaxf(mx, s);
  }
  #pragma unroll
  for (int o = 32; o; o >>= 1) mx = fmaxf(mx, __shfl_xor(mx, o, 64));
  if (lane == 0) rmax[wv] = mx;
  __syncthreads();
  mx = fmaxf(fmaxf(rmax[0],rmax[1]), fmaxf(rmax[2],rmax[3]));
  float sum = 0.f;
  #pragma unroll
  for (int j = 0; j < 4; ++j) { e[j] = __expf(e[j]-mx); sum += e[j]; }
  #pragma unroll
  for (int o = 32; o; o >>= 1) sum += __shfl_xor(sum, o, 64);
  if (lane == 0) rsum[wv] = sum;
  __syncthreads();
  const float inv = 1.f / (rsum[0]+rsum[1]+rsum[2]+rsum[3]);
  float* pr = pall + ((long)w*16 + h)*1024;
  #pragma unroll
  for (int j = 0; j < 4; ++j) {
    const int k = j*256 + t;
    const float pn = e[j]*inv;
    sc[k] = pn;
    pr[k] = pn;
  }
  __syncthreads();
  const u16* vbase = sumkv + (long)w*2097152 + 1024 + h*64;
  float o = 0.f;
  const int k0 = wv*256;
  for (int k = k0; k < k0+256; ++k) o += sc[k] * b2f(vbase[(long)k*2048 + lane]);
  po[wv][lane] = o;
  __syncthreads();
  if (t < 64) content[(long)w*1024 + h*64 + t] = po[0][t]+po[1][t]+po[2][t]+po[3][t];
}

__global__ void wavg_k(const float* pall, float* wavg) {
  const int w = blockIdx.y, k = blockIdx.x*256 + threadIdx.x;
  float s = 0.f;
  #pragma unroll
  for (int h = 0; h < 16; ++h) s += pall[((long)w*16 + h)*1024 + k];
  wavg[w*1024 + k] = s * (1.f/16.f);
}

// ------- content projection -------
__global__ void contproj_k(const float* content, const float* w_, const float* b, float* out) {
  const int w = blockIdx.y, t = threadIdx.x;
  const int nl = t & 63, kq = t >> 6;
  const int n = blockIdx.x*64 + nl;
  const float* c = content + w*1024 + kq*256;
  const float* row = w_ + (long)n * 1024 + kq*256;
  float s = 0.f;
  for (int k = 0; k < 256; k += 4) {
    float4 ww = *(const float4*)&row[k];
    s += c[k]*ww.x + c[k+1]*ww.y + c[k+2]*ww.z + c[k+3]*ww.w;
  }
  __shared__ float ps[4][64];
  ps[kq][nl] = s;
  __syncthreads();
  if (t < 64) out[w*1024 + blockIdx.x*64 + t] = ps[0][t]+ps[1][t]+ps[2][t]+ps[3][t] + b[blockIdx.x*64 + t];
}

// ------- attn_stats phase A -------
__global__ void stats1_k(const float* wavg, float* part) {
  const int c = blockIdx.x, w = blockIdx.y, t = threadIdx.x;
  __shared__ float a[1024];
  for (int i = t; i < 1024; i += 256) a[i] = wavg[w*1024 + i];
  __syncthreads();
  const int jl = t & 63, iq = t >> 6;
  const int j = c*64 + jl;
  const float aj = a[j];
  int pr = 0;
  const int i0 = iq*256;
  #pragma unroll 8
  for (int i = i0; i < i0+256; ++i) {
    const float ai = a[i];
    pr += (ai < aj) || (ai == aj && i < j);
  }
  __shared__ int prs[4][64];
  prs[iq][jl] = pr;
  __syncthreads();
  if (t < 64) {
    const int rank = 1 + prs[0][jl] + prs[1][jl] + prs[2][jl] + prs[3][jl];
    float ent = -aj * logf(aj + 1e-8f);
    float gnum = (float)rank * aj;
    float ssum = aj;
    float mx = aj;
    float top5 = (rank >= 1020) ? aj : 0.f;
    #pragma unroll
    for (int o = 32; o; o >>= 1) {
      ent += __shfl_xor(ent, o, 64);
      gnum += __shfl_xor(gnum, o, 64);
      ssum += __shfl_xor(ssum, o, 64);
      mx = fmaxf(mx, __shfl_xor(mx, o, 64));
      top5 += __shfl_xor(top5, o, 64);
    }
    if (t == 0) {
      float* pp = part + ((w*16 + c) * 5);
      pp[0]=ent; pp[1]=gnum; pp[2]=ssum; pp[3]=mx; pp[4]=top5;
    }
  }
}

// ------- attn_stats phase B -------
__global__ void stats2_k(const float* part, float* stats) {
  const int w = blockIdx.x, t = threadIdx.x;
  const int c = t & 15, stat = t >> 4;
  float v = 0.f;
  const bool active = stat < 5;
  if (active) v = part[(w*16 + c)*5 + stat];
  #pragma unroll
  for (int o = 8; o; o >>= 1) {
    const float ov = __shfl_xor(v, o, 64);
    v = (stat == 3) ? fmaxf(v, ov) : (v + ov);
  }
  __shared__ float r5[5];
  if (active && c == 0) r5[stat] = v;
  __syncthreads();
  if (t == 0) {
    stats[w*4+0] = r5[0];
    stats[w*4+1] = 2.f*r5[1]/(1024.f*r5[2] + 1e-8f) - 1025.f/1024.f;
    stats[w*4+2] = r5[3];
    stats[w*4+3] = r5[4];
  }
}

// ------- pat MLP + summary combine -------
__global__ void patsum_k(const float* stats, const float* contprj,
                         const float* pw1, const float* pb1, const float* pw2, const float* pb2,
                         const float* combw, const float* combb, float* summ) {
  const int w = blockIdx.x, t = threadIdx.x;
  const int nl = t & 63, kq = t >> 6;
  __shared__ float p1[64], pat[64];
  __shared__ float ps[4][64];
  __shared__ float ps2[4][64];
  if (t < 64) {
    float s = 0.f;
    #pragma unroll
    for (int k = 0; k < 4; ++k) s += stats[w*4+k] * pw1[t*4+k];
    p1[t] = fmaxf(s + pb1[t], 0.f);
  }
  __syncthreads();
  {
    float s = 0.f;
    const float* rw = pw2 + (long)nl*64 + kq*16;
    const float* pp = p1 + kq*16;
    #pragma unroll
    for (int k = 0; k < 16; ++k) s += pp[k] * rw[k];
    ps[kq][nl] = s;
  }
  __syncthreads();
  if (t < 64) pat[t] = ps[0][t]+ps[1][t]+ps[2][t]+ps[3][t] + pb2[t];
  __syncthreads();
  const float* c = contprj + w*1024;
  const float* row = combw + (long)nl * 1088;
  float s = 0.f;
  const int k0 = kq*272;
  for (int k = k0; k < k0+272; ++k) {
    const float rv = row[k];
    const float cv = (k < 1024) ? c[k] : pat[k-1024];
    s += cv * rv;
  }
  ps2[kq][nl] = s;
  __syncthreads();
  if (t < 64) summ[w*64 + t] = ps2[0][t]+ps2[1][t]+ps2[2][t]+ps2[3][t] + combb[t];
}

// ---------------- meta attention + routing ----------------
__global__ void meta_k(const float* summ, const float* miw, const float* mib,
                       const float* mow, const float* mob, const float* rw1, const float* rb1,
                       const float* rw2, const float* rb2, float* routing) {
  const int t = threadIdx.x;
  __shared__ float qkv[4][192];
  __shared__ float sc[64];
  __shared__ float o[4][64];
  __shared__ float rf[4][64];
  __shared__ float t1[4][64];
  __shared__ float lg[4];
  for (int idx = t; idx < 768; idx += 64) {
    const int w = idx / 192, rrow = idx % 192;
    const float* rw = miw + (long)rrow * 64;
    float s = 0.f;
    for (int k = 0; k < 64; ++k) s += summ[w*64+k] * rw[k];
    qkv[w][rrow] = s + mib[rrow];
  }
  __syncthreads();
  {
    const int h = t >> 4, i = (t >> 2) & 3, j = t & 3;
    float s = 0.f;
    #pragma unroll
    for (int d = 0; d < 16; ++d) s += qkv[i][h*16+d] * qkv[j][64 + h*16+d];
    sc[t] = s * 0.25f;
  }
  __syncthreads();
  if (t < 16) {
    const float a0=sc[t*4], a1=sc[t*4+1], a2=sc[t*4+2], a3=sc[t*4+3];
    const float m = fmaxf(fmaxf(a0,a1), fmaxf(a2,a3));
    const float e0=__expf(a0-m), e1=__expf(a1-m), e2=__expf(a2-m), e3=__expf(a3-m);
    const float s = e0+e1+e2+e3;
    sc[t*4]=e0/s; sc[t*4+1]=e1/s; sc[t*4+2]=e2/s; sc[t*4+3]=e3/s;
  }
  __syncthreads();
  for (int idx = t; idx < 256; idx += 64) {
    const int i = idx >> 6, c = idx & 63, h = c >> 4;
    float s = 0.f;
    #pragma unroll
    for (int j = 0; j < 4; ++j) s += sc[(h*4+i)*4+j] * qkv[j][128 + c];
    o[i][c] = s;
  }
  __syncthreads();
  for (int idx = t; idx < 256; idx += 64) {
    const int i = idx >> 6, n = idx & 63;
    const float* rw = mow + (long)n * 64;
    float s = 0.f;
    for (int k = 0; k < 64; ++k) s += o[i][k] * rw[k];
    rf[i][n] = s + mob[n];
  }
  __syncthreads();
  for (int idx = t; idx < 256; idx += 64) {
    const int i = idx >> 6, n = idx & 63;
    const float* rw = rw1 + (long)n * 64;
    float s = 0.f;
    for (int k = 0; k < 64; ++k) s += rf[i][k] * rw[k];
    t1[i][n] = fmaxf(s + rb1[n], 0.f);
  }
  __syncthreads();
  if (t < 4) {
    float s = 0.f;
    for (int k = 0; k < 64; ++k) s += t1[t][k] * rw2[k];
    lg[t] = s + rb2[0];
  }
  __syncthreads();
  if (t == 0) {
    const float m = fmaxf(fmaxf(lg[0],lg[1]), fmaxf(lg[2],lg[3]));
    float e[4], s = 0.f;
    #pragma unroll
    for (int i = 0; i < 4; ++i) { e[i] = __expf(lg[i]-m); s += e[i]; }
    #pragma unroll
    for (int i = 0; i < 4; ++i) routing[i] = e[i]/s;
  }
}

// ---------------- routing-weighted kv mix ----------------
__global__ void kvr_k(const u16* local, const float* routing, u16* kvr) {
  const int r = blockIdx.y;
  const long e = ((long)blockIdx.x*256 + threadIdx.x) * 8;
  float rm[4]; float s = 0.f;
  #pragma unroll
  for (int w = 0; w < 4; ++w) { rm[w] = (w == r) ? 0.f : routing[w]; s += rm[w]; }
  const float inv = 1.f / (s + 1e-8f);
  ushort8 a0 = *(const ushort8*)&local[e];
  ushort8 a1 = *(const ushort8*)&local[1048576 + e];
  ushort8 a2 = *(const ushort8*)&local[2097152 + e];
  ushort8 a3 = *(const ushort8*)&local[3145728 + e];
  ushort8 out;
  #pragma unroll
  for (int j = 0; j < 8; ++j)
    out[j] = f2b((rm[0]*b2f(a0[j]) + rm[1]*b2f(a1[j]) + rm[2]*b2f(a2[j]) + rm[3]*b2f(a3[j])) * inv);
  *(ushort8*)&kvr[(long)r*1048576 + e] = out;
}

// ---------------------------------------------------------------------------
template<int BM>
static void gemmT(hipStream_t st, dim3 grid,
                  const u16* A, long lda, const u16* B, long ldb,
                  u16* C, long ldc, const float* bias,
                  int K, int N, float scale, int act, int outf) {
  GemmP p = {};
  p.A=A; p.B=B; p.C=C; p.bias=bias;
  p.lda=lda; p.ldb=ldb; p.ldc=ldc;
  p.K=K; p.Nstore=N; p.ySplit=1<<30; p.act=act; p.outf=outf; p.scale=scale;
  gemm_nt<BM><<<grid, dim3(512), 0, st>>>(p);
}

extern "C" void kernel_launch(void* const* d_in, const int* in_sizes, int n_in,
                              void* d_out, int out_size, void* d_ws, size_t ws_size,
                              hipStream_t stream) {
  (void)in_sizes; (void)n_in; (void)out_size; (void)ws_size;
  const float* x   = (const float*)d_in[0];
  const float* liw = (const float*)d_in[1];
  const float* lib = (const float*)d_in[2];
  const float* low = (const float*)d_in[3];
  const float* lob = (const float*)d_in[4];
  const float* sq  = (const float*)d_in[5];
  const float* siw = (const float*)d_in[6];
  const float* sib = (const float*)d_in[7];
  const float* sow = (const float*)d_in[8];
  const float* sob = (const float*)d_in[9];
  const float* pw1 = (const float*)d_in[10];
  const float* pb1 = (const float*)d_in[11];
  const float* pw2 = (const float*)d_in[12];
  const float* pb2 = (const float*)d_in[13];
  const float* cbw = (const float*)d_in[14];
  const float* cbb = (const float*)d_in[15];
  const float* miw = (const float*)d_in[16];
  const float* mib = (const float*)d_in[17];
  const float* mow = (const float*)d_in[18];
  const float* mob = (const float*)d_in[19];
  const float* rw1 = (const float*)d_in[20];
  const float* rb1 = (const float*)d_in[21];
  const float* rw2 = (const float*)d_in[22];
  const float* rb2 = (const float*)d_in[23];
  const float* ciw = (const float*)d_in[24];
  const float* cib = (const float*)d_in[25];
  const float* cow = (const float*)d_in[26];
  const float* cob = (const float*)d_in[27];
  const float* gw  = (const float*)d_in[28];
  const float* gb  = (const float*)d_in[29];
  const float* pw  = (const float*)d_in[30];
  const float* pb  = (const float*)d_in[31];

  char* ws = (char*)d_ws;
  u16* qkv    = (u16*)(ws + 0);
  u16* aout   = (u16*)(ws + 25165824);
  u16* local  = (u16*)(ws + 33554432);
  u16* scratch= (u16*)(ws + 41943040);
  u16* s2048  = (u16*)(ws + 79691776);
  u16* cq     = (u16*)(ws + 96468992);
  u16* kvr    = (u16*)(ws + 104857600);
  u16* crossb = (u16*)(ws + 113246208);
  char* sf = ws + 121634816;
  float* qs      = (float*)(sf + 0);
  float* pall    = (float*)(sf + 4096);
  float* wavg    = (float*)(sf + 266240);
  float* content = (float*)(sf + 282624);
  float* contprj = (float*)(sf + 299008);
  float* stats   = (float*)(sf + 315392);
  float* summ    = (float*)(sf + 315456);
  float* routing = (float*)(sf + 316480);
  float* part    = (float*)(sf + 316544);
  u16* siwkvb = (u16*)(ws + 122028032);
  u16* lowb   = (u16*)(ws + 126222336);
  u16* ciwb   = (u16*)(ws + 128319488);
  u16* cowb   = (u16*)(ws + 134610944);
  u16* gwb    = (u16*)(ws + 136708096);
  u16* pwb    = (u16*)(ws + 140902400);
  u16* xb   = crossb;
  u16* liwb = scratch;

  // 0. fp32 -> bf16 conversions
  CvtP cp;
  cp.src[0]=x;   cp.dst[0]=xb;     cp.n[0]=4194304;
  cp.src[1]=liw; cp.dst[1]=liwb;   cp.n[1]=3145728;
  cp.src[2]=low; cp.dst[2]=lowb;   cp.n[2]=1048576;
  cp.src[3]=siw+1048576; cp.dst[3]=siwkvb; cp.n[3]=2097152;
  cp.src[4]=ciw; cp.dst[4]=ciwb;   cp.n[4]=3145728;
  cp.src[5]=cow; cp.dst[5]=cowb;   cp.n[5]=1048576;
  cp.src[6]=gw;  cp.dst[6]=gwb;    cp.n[6]=2097152;
  cp.src[7]=pw;  cp.dst[7]=pwb;    cp.n[7]=1048576;
  cvt_multi<<<dim3(2048, 8), dim3(256), 0, stream>>>(cp);

  // 1. local QKV projection (BM=128, grid 768 = 3 blocks/CU)
  gemmT<128>(stream, dim3(32,24), xb,1024, liwb,1024, qkv,3072, lib, 1024, 3072, 1.f, 0, 0);

  // 2. fused local self-attention (XCD-swizzled 1-D grid)
  {
    FlashP fp;
    fp.q = qkv; fp.k = qkv + 1024; fp.v = qkv + 2048; fp.o = aout;
    fp.ldq = 3072; fp.ldkv = 3072; fp.ldo = 1024;
    fp.qB = 3145728; fp.kvB = 3145728; fp.oB = 1048576;
    flash_k<<<dim3(512), dim3(256), 0, stream>>>(fp);
  }

  // 3. local out-projection (BM=64, grid 512 = 2 blocks/CU)
  gemmT<64>(stream, dim3(64,8), aout,1024, lowb,1024, local,1024, lob, 1024, 1024, 1.f, 0, 0);

  // 4. combined crossQ (y<8) + summary K/V (y>=8) projections (BM=128, 768 blocks)
  {
    GemmP p = {};
    p.A = local; p.lda = 1024; p.K = 1024; p.scale = 1.f;
    p.B = ciwb;   p.C = cq;    p.bias = cib;      p.ldb = 1024; p.ldc = 1024; p.Nstore = 1024;
    p.B2 = siwkvb; p.C2 = s2048; p.bias2 = sib+1024; p.ldb2 = 1024; p.ldc2 = 2048; p.Nstore2 = 2048;
    p.ySplit = 8;
    gemm_nt<128><<<dim3(32,24), dim3(512), 0, stream>>>(p);
  }

  // 5. summaries
  gemv_qs<<<dim3(16), dim3(256), 0, stream>>>(sq, siw, sib, qs);
  sum_attend<<<dim3(16,4), dim3(256), 0, stream>>>(qs, s2048, content, pall);
  wavg_k<<<dim3(4,4), dim3(256), 0, stream>>>(pall, wavg);
  contproj_k<<<dim3(16,4), dim3(256), 0, stream>>>(content, sow, sob, contprj);
  stats1_k<<<dim3(16,4), dim3(256), 0, stream>>>(wavg, part);
  stats2_k<<<dim3(4), dim3(128), 0, stream>>>(part, stats);
  patsum_k<<<dim3(4), dim3(256), 0, stream>>>(stats, contprj, pw1, pb1, pw2, pb2, cbw, cbb, summ);

  // 6. meta attention + routing
  meta_k<<<dim3(1), dim3(64), 0, stream>>>(summ, miw, mib, mow, mob, rw1, rb1, rw2, rb2, routing);

  // 7. per-rank mixed kv
  kvr_k<<<dim3(512,4), dim3(256), 0, stream>>>(local, routing, kvr);

  // 8. cross K/V projection (BM=128, grid 512 = 2 blocks/CU)
  gemmT<128>(stream, dim3(32,16), kvr,1024, ciwb+1048576,1024, s2048,2048, cib+1024, 1024, 2048, 1.f, 0, 0);

  // 9. fused cross attention (XCD-swizzled 1-D grid)
  {
    FlashP fp;
    fp.q = cq; fp.k = s2048; fp.v = s2048 + 1024; fp.o = aout;
    fp.ldq = 1024; fp.ldkv = 2048; fp.ldo = 1024;
    fp.qB = 1048576; fp.kvB = 2097152; fp.oB = 1048576;
    flash_k<<<dim3(512), dim3(256), 0, stream>>>(fp);
  }

  // 10. cross out-projection (BM=64)
  gemmT<64>(stream, dim3(64,8), aout,1024, cowb,1024, crossb,1024, cob, 1024, 1024, 1.f, 0, 0);

  // 11. gate GEMM (dual-K, BM=64) with fused sigmoid+comb
  {
    GemmP p = {};
    p.A = local; p.A2 = crossb; p.lr = local; p.cr = crossb;
    p.B = gwb; p.C = kvr; p.bias = gb;
    p.lda = 1024; p.ldb = 2048; p.ldc = 1024;
    p.K = 1024; p.Nstore = 1024; p.ySplit = 1<<30; p.act = 2; p.outf = 0; p.scale = 1.f;
    gemm_nt<64><<<dim3(64,8), dim3(512), 0, stream>>>(p);
  }

  // 12. final projection -> d_out (fp32, BM=64)
  gemmT<64>(stream, dim3(64,8), kvr,1024, pwb,1024, (u16*)d_out,1024, pb, 1024, 1024, 1.f, 0, 1);
}